// Round 5
// baseline (285.332 us; speedup 1.0000x reference)
//
#include <hip/hip_runtime.h>
#include <cstdint>
#include <cstddef>

#define D 256
#define HEADS 8
#define HD 32
#define NB 2
#define LQ 12240
#define NQ (NB * LQ)        // 24480
#define PLANE (LQ * HD)     // 391680 elements per (n,h) plane

typedef __attribute__((ext_vector_type(8))) short bf16x8;
typedef __attribute__((ext_vector_type(4))) float f32x4;
typedef __bf16 bf16x2 __attribute__((ext_vector_type(2)));

__device__ __forceinline__ ushort f2bf(float f) {
    union { float f; uint32_t u; } c; c.f = f;
    uint32_t u = c.u;
    uint32_t r = (u + 0x7fffu + ((u >> 16) & 1u)) >> 16;   // RNE, finite inputs
    return (ushort)r;
}

// c += a_pair . b_pair  (bf16 pairs packed in u32, f32 accumulate)
__device__ __forceinline__ float dot2bf(uint32_t a, uint32_t b, float c) {
#if __has_builtin(__builtin_amdgcn_fdot2_f32_bf16)
    return __builtin_amdgcn_fdot2_f32_bf16(__builtin_bit_cast(bf16x2, a),
                                           __builtin_bit_cast(bf16x2, b), c, false);
#else
    float alo = __uint_as_float(a << 16), ahi = __uint_as_float(a & 0xffff0000u);
    float blo = __uint_as_float(b << 16), bhi = __uint_as_float(b & 0xffff0000u);
    return c + alo * blo + ahi * bhi;
#endif
}

// ---------------------------------------------------------------------------
// K0: weight/bias conversion (unchanged).
// ---------------------------------------------------------------------------
__global__ __launch_bounds__(256) void conv_kernel(
    const float* __restrict__ w_value, const float* __restrict__ w_off,
    const float* __restrict__ w_attn,  const float* __restrict__ b_value,
    const float* __restrict__ b_off,   const float* __restrict__ b_attn,
    const float* __restrict__ w_out,
    ushort* __restrict__ B_pack, ushort* __restrict__ w_out_t,
    float* __restrict__ b_pack)
{
    const int b = blockIdx.x, k = threadIdx.x;
    if (b < 640) {
        float v;
        if (b < 256)      v = w_value[(size_t)k * 256 + b];
        else if (b < 512) v = w_off[(size_t)k * 256 + (b - 256)];
        else              v = w_attn[(size_t)k * 128 + (b - 512)];
        B_pack[(size_t)b * 256 + k] = f2bf(v);
    } else if (b < 896) {
        int n = b - 640;
        w_out_t[(size_t)n * 256 + k] = f2bf(w_out[(size_t)k * 256 + n]);
    } else if (b == 896) {
        b_pack[k] = b_value[k];
    } else if (b == 897) {
        b_pack[256 + k] = b_off[k];
    } else {
        if (k < 128) b_pack[512 + k] = b_attn[k];
    }
}

// ---------------------------------------------------------------------------
// K1: fused projections via MFMA -- LDS-free, barrier-free.
// A fragments loaded global->reg (fp32->bf16 in regs, read once per y-half);
// B fragments loaded global->reg per MFMA (B-tile is L1/L2-resident; all 4
// waves share it).  No __syncthreads anywhere -> waves free-run, stores
// overlap the next tile's loads/MFMAs.
// ---------------------------------------------------------------------------
__global__ __launch_bounds__(256) void proj_gemm(
    const float* __restrict__ src, const ushort* __restrict__ B_pack,
    const float* __restrict__ b_pack,
    ushort* __restrict__ val_t, float* __restrict__ off_raw,
    float* __restrict__ attn_raw)
{
    const int tid = threadIdx.x;
    const int m0  = blockIdx.x * 64;
    const int wv = tid >> 6, lane = tid & 63;
    const int quad = lane >> 4, ln = lane & 15;

    // ---- A fragments: row (m0 + wv*16 + ln), k = s*32 + quad*8 .. +8
    const int row_a = m0 + wv * 16 + ln;
    const bool va = row_a < NQ;
    const float* ap = src + (size_t)row_a * 256 + quad * 8;
    bf16x8 af[8];
#pragma unroll
    for (int s = 0; s < 8; ++s) {
        float4 lo = {0, 0, 0, 0}, hi = {0, 0, 0, 0};
        if (va) {
            lo = *(const float4*)(ap + s * 32);
            hi = *(const float4*)(ap + s * 32 + 4);
        }
        bf16x8 o;
        o[0] = (short)f2bf(lo.x); o[1] = (short)f2bf(lo.y);
        o[2] = (short)f2bf(lo.z); o[3] = (short)f2bf(lo.w);
        o[4] = (short)f2bf(hi.x); o[5] = (short)f2bf(hi.y);
        o[6] = (short)f2bf(hi.z); o[7] = (short)f2bf(hi.w);
        af[s] = o;
    }

    for (int bi = 0; bi < 5; ++bi) {
        const int by = blockIdx.y * 5 + bi;
        // B fragment base for this lane: row (by*64 + t*16 + ln), k = s*32+quad*8
        const ushort* bp = B_pack + (size_t)(by * 64 + ln) * 256 + quad * 8;

        f32x4 acc[4] = {{0,0,0,0},{0,0,0,0},{0,0,0,0},{0,0,0,0}};
#pragma unroll
        for (int s = 0; s < 8; ++s) {
#pragma unroll
            for (int t = 0; t < 4; ++t) {
                bf16x8 bfr = *(const bf16x8*)(bp + (size_t)t * 4096 + s * 32);
                acc[t] = __builtin_amdgcn_mfma_f32_16x16x32_bf16(af[s], bfr, acc[t], 0, 0, 0);
            }
        }

#pragma unroll
        for (int t = 0; t < 4; ++t) {
            int n_g = by * 64 + t * 16 + ln;
            float bias = b_pack[n_g];
#pragma unroll
            for (int reg = 0; reg < 4; ++reg) {
                int row = m0 + wv * 16 + quad * 4 + reg;
                if (row < NQ) {
                    float v = acc[t][reg] + bias;
                    if (n_g < 256) {
                        int h = n_g >> 5, hd = n_g & 31;
                        int nb = row >= LQ; int ql = row - nb * LQ;
                        val_t[(((size_t)(nb * 8 + h)) * LQ + ql) * 32 + hd] = f2bf(v);
                    } else if (n_g < 512) {
                        off_raw[(size_t)row * 256 + (n_g - 256)] = v;
                    } else {
                        attn_raw[(size_t)row * 128 + (n_g - 512)] = v;
                    }
                }
            }
        }
    }
}

// ---------------------------------------------------------------------------
// K1b: build x-pair table (unchanged).
// ---------------------------------------------------------------------------
__global__ __launch_bounds__(256) void pair_kernel(
    const ushort* __restrict__ val_t, uint32_t* __restrict__ val_pair)
{
    const uint32_t i = blockIdx.x * 256 + threadIdx.x;   // < 6,266,880
    const uint32_t c = i & 31;
    const uint32_t rest = i >> 5;                        // plane*12240 + pos
    const uint32_t plane = rest / LQ;
    const uint32_t pos = rest - plane * LQ;
    int l = (pos >= 9216) + (pos >= 11520) + (pos >= 12096);
    uint32_t s0 = (l > 0 ? 9216u : 0u) + (l > 1 ? 2304u : 0u) + (l > 2 ? 576u : 0u);
    uint32_t Wi = 96u >> l;
    uint32_t p = pos - s0;
    uint32_t q = (p / 3u) >> (5 - l);          // p / Wi  (Wi = 3<<(5-l))
    uint32_t xr = p - q * Wi;                  // p % Wi
    uint32_t nxt = (xr == Wi - 1u) ? pos : pos + 1u;
    uint32_t lo = val_t[(size_t)plane * PLANE + pos * 32 + c];
    uint32_t hi = val_t[(size_t)plane * PLANE + nxt * 32 + c];
    val_pair[i] = lo | (hi << 16);
}

// ---------------------------------------------------------------------------
// K2: softmax + sampling + bilinear gather via x-pair table + dot2
// (unchanged from R4).
// ---------------------------------------------------------------------------
__global__ __launch_bounds__(256) void sample_kernel(
    const float* __restrict__ ref_pts,
    const uint32_t* __restrict__ val_pair,
    const float* __restrict__ off_raw,
    const float* attn_raw,
    uint32_t* sampled)
{
    __shared__ uint4 sm[16][16];
    const int gl = threadIdx.x >> 4;
    const int ln = threadIdx.x & 15;
    const int g  = blockIdx.x * 16 + gl;
    const int qg = g >> 3, h = g & 7;
    const int n  = (qg >= LQ) ? 1 : 0;
    const int l  = ln >> 2;

    float a = attn_raw[(size_t)qg * 128 + h * 16 + ln];
    float m = a;
#pragma unroll
    for (int s = 8; s; s >>= 1) m = fmaxf(m, __shfl_xor(m, s, 16));
    float e = __expf(a - m);
    float ssum = e;
#pragma unroll
    for (int s = 8; s; s >>= 1) ssum += __shfl_xor(ssum, s, 16);
    float aw = e / ssum;

    float ox = off_raw[(size_t)qg * 256 + h * 32 + ln * 2 + 0];
    float oy = off_raw[(size_t)qg * 256 + h * 32 + ln * 2 + 1];
    float rx = ref_pts[(qg * 4 + l) * 2 + 0];
    float ry = ref_pts[(qg * 4 + l) * 2 + 1];

    const int Wi = 96 >> l;
    const int Hi = Wi;
    const int s0 = (l > 0 ? 9216 : 0) + (l > 1 ? 2304 : 0) + (l > 2 ? 576 : 0);
    const float Wf = (float)Wi, Hf = (float)Hi;

    float x = (rx + ox / Wf) * Wf - 0.5f;
    float y = (ry + oy / Hf) * Hf - 0.5f;
    float x0f = floorf(x), y0f = floorf(y);
    float lx = x - x0f, ly = y - y0f;
    int x0 = (int)x0f, y0 = (int)y0f;

    float wy0 = (y0 >= 0 && y0 < Hi) ? (1.f - ly) : 0.f;
    float wy1 = (y0 + 1 >= 0 && y0 + 1 < Hi) ? ly : 0.f;
    int yc0 = min(max(y0, 0), Hi - 1);
    int yc1 = min(max(y0 + 1, 0), Hi - 1);
    float wl = (x0 >= 0 && x0 < Wi) ? (1.f - lx) : 0.f;
    float wh = (x0 + 1 >= 0 && x0 + 1 < Wi) ? lx : 0.f;
    float pl, ph;
    int xe;
    if (x0 < 0) { pl = wh; ph = 0.f; xe = x0 + 1; }
    else        { pl = wl; ph = wh;  xe = x0; }
    int xc = min(max(xe, 0), Wi - 1);
    pl *= aw; ph *= aw;

    uint32_t wp0 = ((uint32_t)f2bf(ph * wy0) << 16) | (uint32_t)f2bf(pl * wy0);
    uint32_t wp1 = ((uint32_t)f2bf(ph * wy1) << 16) | (uint32_t)f2bf(pl * wy1);
    uint32_t idx0 = (uint32_t)(s0 + yc0 * Wi + xc) * 32u;
    uint32_t idx1 = (uint32_t)(s0 + yc1 * Wi + xc) * 32u;

    sm[gl][ln] = make_uint4(idx0, idx1, wp0, wp1);
    // intra-wave LDS write->read: compiler-inserted lgkmcnt orders it

    const uint32_t* plane =
        val_pair + (size_t)(n * HEADS + h) * PLANE + 2 * ln;
    float a0 = 0.f, a1 = 0.f;
#pragma unroll
    for (int p = 0; p < 16; ++p) {
        uint4 ent = sm[gl][p];
        uint2 r0 = *(const uint2*)(plane + ent.x);
        uint2 r1 = *(const uint2*)(plane + ent.y);
        a0 = dot2bf(r0.x, ent.z, a0);
        a1 = dot2bf(r0.y, ent.z, a1);
        a0 = dot2bf(r1.x, ent.w, a0);
        a1 = dot2bf(r1.y, ent.w, a1);
    }
    uint32_t r = ((uint32_t)f2bf(a1) << 16) | (uint32_t)f2bf(a0);
    sampled[(size_t)qg * 128 + h * 16 + ln] = r;
}

// ---------------------------------------------------------------------------
// K3: fused out-proj + residual + LayerNorm -- LDS-free, barrier-free.
// A (sampled, bf16) and B (w_out_t) fragments loaded global->reg; all 4
// N-tiles of accumulator kept in registers; LN stats via width-16 shuffles;
// gamma/beta/b_out read direct from global (L1-hot across 383 blocks).
// ---------------------------------------------------------------------------
__global__ __launch_bounds__(256) void out_ln_gemm(
    const ushort* __restrict__ sampled, const ushort* __restrict__ w_out_t,
    const float* __restrict__ b_out,    const float* __restrict__ src,
    const float* __restrict__ gamma,    const float* __restrict__ beta,
    float* __restrict__ out)
{
    const int tid = threadIdx.x;
    const int m0  = blockIdx.x * 64;
    const int wv = tid >> 6, lane = tid & 63;
    const int quad = lane >> 4, ln = lane & 15;

    // A fragments
    const int row_a = m0 + wv * 16 + ln;
    const bool va = row_a < NQ;
    const ushort* ap = sampled + (size_t)row_a * 256 + quad * 8;
    bf16x8 af[8];
#pragma unroll
    for (int s = 0; s < 8; ++s) {
        bf16x8 v = {0, 0, 0, 0, 0, 0, 0, 0};
        if (va) v = *(const bf16x8*)(ap + s * 32);
        af[s] = v;
    }

    f32x4 acc[4][4];
#pragma unroll
    for (int by = 0; by < 4; ++by)
#pragma unroll
        for (int t = 0; t < 4; ++t) acc[by][t] = (f32x4){0, 0, 0, 0};

    const ushort* bp = w_out_t + (size_t)ln * 256 + quad * 8;
#pragma unroll
    for (int by = 0; by < 4; ++by) {
#pragma unroll
        for (int s = 0; s < 8; ++s) {
#pragma unroll
            for (int t = 0; t < 4; ++t) {
                bf16x8 bfr = *(const bf16x8*)(bp + (size_t)(by * 64 + t * 16) * 256 + s * 32);
                acc[by][t] = __builtin_amdgcn_mfma_f32_16x16x32_bf16(af[s], bfr, acc[by][t], 0, 0, 0);
            }
        }
    }

    // epilogue: residual + bias, LN stats per row (16 cols/thread, x16 lanes)
#pragma unroll
    for (int reg = 0; reg < 4; ++reg) {
        const int row = m0 + wv * 16 + quad * 4 + reg;
        const bool vr = row < NQ;
        float xv[16];
        float s = 0.f, s2 = 0.f;
#pragma unroll
        for (int bt = 0; bt < 16; ++bt) {
            int col = bt * 16 + ln;
            float v = acc[bt >> 2][bt & 3][reg] + b_out[col];
            if (vr) v += src[(size_t)row * 256 + col];
            xv[bt] = v;
            s += v; s2 += v * v;
        }
#pragma unroll
        for (int o = 8; o; o >>= 1) {
            s  += __shfl_xor(s, o, 16);
            s2 += __shfl_xor(s2, o, 16);
        }
        float mu  = s * (1.f / 256.f);
        float var = s2 * (1.f / 256.f) - mu * mu;
        float rs  = rsqrtf(var + 1e-5f);
        if (vr) {
#pragma unroll
            for (int bt = 0; bt < 16; ++bt) {
                int col = bt * 16 + ln;
                out[(size_t)row * 256 + col] = (xv[bt] - mu) * rs * gamma[col] + beta[col];
            }
        }
    }
}

// ---------------------------------------------------------------------------
extern "C" void kernel_launch(void* const* d_in, const int* in_sizes, int n_in,
                              void* d_out, int out_size, void* d_ws, size_t ws_size,
                              hipStream_t stream)
{
    const float* src     = (const float*)d_in[0];
    const float* refp    = (const float*)d_in[1];
    const float* w_value = (const float*)d_in[4];
    const float* b_value = (const float*)d_in[5];
    const float* w_off   = (const float*)d_in[6];
    const float* b_off   = (const float*)d_in[7];
    const float* w_attn  = (const float*)d_in[8];
    const float* b_attn  = (const float*)d_in[9];
    const float* w_out   = (const float*)d_in[10];
    const float* b_out   = (const float*)d_in[11];
    const float* gamma   = (const float*)d_in[12];
    const float* beta    = (const float*)d_in[13];

    char* ws = (char*)d_ws;
    ushort*   val_t    = (ushort*)  (ws);                   // 12,533,760 B
    uint32_t* val_pair = (uint32_t*)(ws + 12533760);        // 25,067,520 B
    float*    off_raw  = (float*)   (ws + 37601280);        // 25,067,520 B
    float*    attn_raw = (float*)   (ws + 62668800);        // 12,533,760 B
    uint32_t* sampled  = (uint32_t*)(ws + 62668800);        // alias of attn_raw (safe: K2)
    ushort*   B_pack   = (ushort*)  (ws + 75202560);        //    327,680 B
    ushort*   w_out_t  = (ushort*)  (ws + 75530240);        //    131,072 B
    float*    b_pack   = (float*)   (ws + 75661312);        //      2,560 B
    float*    out      = (float*)d_out;

    conv_kernel<<<899, 256, 0, stream>>>(w_value, w_off, w_attn, b_value, b_off,
                                         b_attn, w_out, B_pack, w_out_t, b_pack);
    proj_gemm<<<dim3(383, 2), 256, 0, stream>>>(src, B_pack, b_pack, val_t,
                                                off_raw, attn_raw);
    pair_kernel<<<24480, 256, 0, stream>>>(val_t, val_pair);
    sample_kernel<<<12240, 256, 0, stream>>>(refp, val_pair, off_raw, attn_raw,
                                             sampled);
    out_ln_gemm<<<383, 256, 0, stream>>>((const ushort*)sampled, w_out_t, b_out,
                                         src, gamma, beta, out);
}

// Round 6
// 255.774 us; speedup vs baseline: 1.1156x; 1.1156x over previous
//
#include <hip/hip_runtime.h>
#include <cstdint>
#include <cstddef>

#define D 256
#define HEADS 8
#define HD 32
#define NB 2
#define LQ 12240
#define NQ (NB * LQ)        // 24480
#define PLANE (LQ * HD)     // 391680 elements per (n,h) plane

typedef __attribute__((ext_vector_type(8))) short bf16x8;
typedef __attribute__((ext_vector_type(4))) float f32x4;
typedef __bf16 bf16x2 __attribute__((ext_vector_type(2)));

__device__ __forceinline__ ushort f2bf(float f) {
    union { float f; uint32_t u; } c; c.f = f;
    uint32_t u = c.u;
    uint32_t r = (u + 0x7fffu + ((u >> 16) & 1u)) >> 16;   // RNE, finite inputs
    return (ushort)r;
}

// c += a_pair . b_pair  (bf16 pairs packed in u32, f32 accumulate)
__device__ __forceinline__ float dot2bf(uint32_t a, uint32_t b, float c) {
#if __has_builtin(__builtin_amdgcn_fdot2_f32_bf16)
    return __builtin_amdgcn_fdot2_f32_bf16(__builtin_bit_cast(bf16x2, a),
                                           __builtin_bit_cast(bf16x2, b), c, false);
#else
    float alo = __uint_as_float(a << 16), ahi = __uint_as_float(a & 0xffff0000u);
    float blo = __uint_as_float(b << 16), bhi = __uint_as_float(b & 0xffff0000u);
    return c + alo * blo + ahi * bhi;
#endif
}

// ---------------------------------------------------------------------------
// K0: weight/bias conversion (unchanged).
// ---------------------------------------------------------------------------
__global__ __launch_bounds__(256) void conv_kernel(
    const float* __restrict__ w_value, const float* __restrict__ w_off,
    const float* __restrict__ w_attn,  const float* __restrict__ b_value,
    const float* __restrict__ b_off,   const float* __restrict__ b_attn,
    const float* __restrict__ w_out,
    ushort* __restrict__ B_pack, ushort* __restrict__ w_out_t,
    float* __restrict__ b_pack)
{
    const int b = blockIdx.x, k = threadIdx.x;
    if (b < 640) {
        float v;
        if (b < 256)      v = w_value[(size_t)k * 256 + b];
        else if (b < 512) v = w_off[(size_t)k * 256 + (b - 256)];
        else              v = w_attn[(size_t)k * 128 + (b - 512)];
        B_pack[(size_t)b * 256 + k] = f2bf(v);
    } else if (b < 896) {
        int n = b - 640;
        w_out_t[(size_t)n * 256 + k] = f2bf(w_out[(size_t)k * 256 + n]);
    } else if (b == 896) {
        b_pack[k] = b_value[k];
    } else if (b == 897) {
        b_pack[256 + k] = b_off[k];
    } else {
        if (k < 128) b_pack[512 + k] = b_attn[k];
    }
}

// ---------------------------------------------------------------------------
// K0b: src fp32 -> bf16 (row-major, 4 elems/thread).
// ---------------------------------------------------------------------------
__global__ __launch_bounds__(256) void src2bf_kernel(
    const float* __restrict__ src, ushort* __restrict__ src_bf)
{
    const size_t i = ((size_t)blockIdx.x * 256 + threadIdx.x) * 4;
    float4 v = *(const float4*)(src + i);
    ushort4 o;
    o.x = f2bf(v.x); o.y = f2bf(v.y); o.z = f2bf(v.z); o.w = f2bf(v.w);
    *(ushort4*)(src_bf + i) = o;
}

// ---------------------------------------------------------------------------
// K1: fused projections via MFMA -- B-stationary in registers.
// Grid (64 M-chunks, 10 N-tiles).  Each block loads its N-tile's full
// fragment set ONCE (bfr[4][8] = 128 VGPRs, forced live by the explicit
// array + launch_bounds(256,2)), then loops 6 M-tiles of 64 rows with no
// barriers: 8 A-frag loads (bf16, one dwordx4 each) -> 32 MFMAs -> uniform
// epilogue (each by maps to exactly one destination tensor).
// A re-reads across the 10 by-values are LLC-served (src_bf = 12.5 MB).
// ---------------------------------------------------------------------------
__global__ __launch_bounds__(256, 2) void proj_gemm(
    const ushort* __restrict__ src_bf, const ushort* __restrict__ B_pack,
    const float* __restrict__ b_pack,
    ushort* __restrict__ val_t, float* __restrict__ off_raw,
    float* __restrict__ attn_raw)
{
    const int tid = threadIdx.x;
    const int wv = tid >> 6, lane = tid & 63;
    const int quad = lane >> 4, ln = lane & 15;
    const int mc = blockIdx.x;          // 0..63
    const int by = blockIdx.y;          // 0..9

    // ---- B fragments for this N-tile (held across the whole M-loop)
    const ushort* bp = B_pack + (size_t)(by * 64 + ln) * 256 + quad * 8;
    bf16x8 bfr[4][8];
#pragma unroll
    for (int t = 0; t < 4; ++t)
#pragma unroll
        for (int s = 0; s < 8; ++s)
            bfr[t][s] = *(const bf16x8*)(bp + (size_t)t * (16 * 256) + s * 32);

    float bias[4];
#pragma unroll
    for (int t = 0; t < 4; ++t) bias[t] = b_pack[by * 64 + t * 16 + ln];

    for (int i = 0; i < 6; ++i) {
        const int base = (mc * 6 + i) * 64;
        if (base >= NQ) break;
        const int row_a = base + wv * 16 + ln;
        const bool va = row_a < NQ;
        const ushort* ap = src_bf + (size_t)row_a * 256 + quad * 8;

        bf16x8 af[8];
#pragma unroll
        for (int s = 0; s < 8; ++s) {
            bf16x8 v = {0, 0, 0, 0, 0, 0, 0, 0};
            if (va) v = *(const bf16x8*)(ap + s * 32);
            af[s] = v;
        }

        f32x4 acc[4] = {{0,0,0,0},{0,0,0,0},{0,0,0,0},{0,0,0,0}};
#pragma unroll
        for (int s = 0; s < 8; ++s)
#pragma unroll
            for (int t = 0; t < 4; ++t)
                acc[t] = __builtin_amdgcn_mfma_f32_16x16x32_bf16(af[s], bfr[t][s], acc[t], 0, 0, 0);

        // ---- epilogue: destination is uniform per by
        if (by < 4) {
#pragma unroll
            for (int t = 0; t < 4; ++t) {
                const int n_g = by * 64 + t * 16 + ln;
                const int h = n_g >> 5, hd = n_g & 31;
#pragma unroll
                for (int reg = 0; reg < 4; ++reg) {
                    int row = base + wv * 16 + quad * 4 + reg;
                    if (row < NQ) {
                        int nb = row >= LQ; int ql = row - nb * LQ;
                        val_t[(((size_t)(nb * 8 + h)) * LQ + ql) * 32 + hd] =
                            f2bf(acc[t][reg] + bias[t]);
                    }
                }
            }
        } else if (by < 8) {
#pragma unroll
            for (int t = 0; t < 4; ++t) {
                const int col = (by - 4) * 64 + t * 16 + ln;
#pragma unroll
                for (int reg = 0; reg < 4; ++reg) {
                    int row = base + wv * 16 + quad * 4 + reg;
                    if (row < NQ)
                        off_raw[(size_t)row * 256 + col] = acc[t][reg] + bias[t];
                }
            }
        } else {
#pragma unroll
            for (int t = 0; t < 4; ++t) {
                const int col = (by - 8) * 64 + t * 16 + ln;
#pragma unroll
                for (int reg = 0; reg < 4; ++reg) {
                    int row = base + wv * 16 + quad * 4 + reg;
                    if (row < NQ)
                        attn_raw[(size_t)row * 128 + col] = acc[t][reg] + bias[t];
                }
            }
        }
    }
}

// ---------------------------------------------------------------------------
// K1b: build x-pair table (unchanged).
// ---------------------------------------------------------------------------
__global__ __launch_bounds__(256) void pair_kernel(
    const ushort* __restrict__ val_t, uint32_t* __restrict__ val_pair)
{
    const uint32_t i = blockIdx.x * 256 + threadIdx.x;   // < 6,266,880
    const uint32_t c = i & 31;
    const uint32_t rest = i >> 5;                        // plane*12240 + pos
    const uint32_t plane = rest / LQ;
    const uint32_t pos = rest - plane * LQ;
    int l = (pos >= 9216) + (pos >= 11520) + (pos >= 12096);
    uint32_t s0 = (l > 0 ? 9216u : 0u) + (l > 1 ? 2304u : 0u) + (l > 2 ? 576u : 0u);
    uint32_t Wi = 96u >> l;
    uint32_t p = pos - s0;
    uint32_t q = (p / 3u) >> (5 - l);          // p / Wi  (Wi = 3<<(5-l))
    uint32_t xr = p - q * Wi;                  // p % Wi
    uint32_t nxt = (xr == Wi - 1u) ? pos : pos + 1u;
    uint32_t lo = val_t[(size_t)plane * PLANE + pos * 32 + c];
    uint32_t hi = val_t[(size_t)plane * PLANE + nxt * 32 + c];
    val_pair[i] = lo | (hi << 16);
}

// ---------------------------------------------------------------------------
// K2: softmax + sampling + bilinear gather via x-pair table + dot2
// (unchanged).
// ---------------------------------------------------------------------------
__global__ __launch_bounds__(256) void sample_kernel(
    const float* __restrict__ ref_pts,
    const uint32_t* __restrict__ val_pair,
    const float* __restrict__ off_raw,
    const float* attn_raw,
    uint32_t* sampled)
{
    __shared__ uint4 sm[16][16];
    const int gl = threadIdx.x >> 4;
    const int ln = threadIdx.x & 15;
    const int g  = blockIdx.x * 16 + gl;
    const int qg = g >> 3, h = g & 7;
    const int n  = (qg >= LQ) ? 1 : 0;
    const int l  = ln >> 2;

    float a = attn_raw[(size_t)qg * 128 + h * 16 + ln];
    float m = a;
#pragma unroll
    for (int s = 8; s; s >>= 1) m = fmaxf(m, __shfl_xor(m, s, 16));
    float e = __expf(a - m);
    float ssum = e;
#pragma unroll
    for (int s = 8; s; s >>= 1) ssum += __shfl_xor(ssum, s, 16);
    float aw = e / ssum;

    float ox = off_raw[(size_t)qg * 256 + h * 32 + ln * 2 + 0];
    float oy = off_raw[(size_t)qg * 256 + h * 32 + ln * 2 + 1];
    float rx = ref_pts[(qg * 4 + l) * 2 + 0];
    float ry = ref_pts[(qg * 4 + l) * 2 + 1];

    const int Wi = 96 >> l;
    const int Hi = Wi;
    const int s0 = (l > 0 ? 9216 : 0) + (l > 1 ? 2304 : 0) + (l > 2 ? 576 : 0);
    const float Wf = (float)Wi, Hf = (float)Hi;

    float x = (rx + ox / Wf) * Wf - 0.5f;
    float y = (ry + oy / Hf) * Hf - 0.5f;
    float x0f = floorf(x), y0f = floorf(y);
    float lx = x - x0f, ly = y - y0f;
    int x0 = (int)x0f, y0 = (int)y0f;

    float wy0 = (y0 >= 0 && y0 < Hi) ? (1.f - ly) : 0.f;
    float wy1 = (y0 + 1 >= 0 && y0 + 1 < Hi) ? ly : 0.f;
    int yc0 = min(max(y0, 0), Hi - 1);
    int yc1 = min(max(y0 + 1, 0), Hi - 1);
    float wl = (x0 >= 0 && x0 < Wi) ? (1.f - lx) : 0.f;
    float wh = (x0 + 1 >= 0 && x0 + 1 < Wi) ? lx : 0.f;
    float pl, ph;
    int xe;
    if (x0 < 0) { pl = wh; ph = 0.f; xe = x0 + 1; }
    else        { pl = wl; ph = wh;  xe = x0; }
    int xc = min(max(xe, 0), Wi - 1);
    pl *= aw; ph *= aw;

    uint32_t wp0 = ((uint32_t)f2bf(ph * wy0) << 16) | (uint32_t)f2bf(pl * wy0);
    uint32_t wp1 = ((uint32_t)f2bf(ph * wy1) << 16) | (uint32_t)f2bf(pl * wy1);
    uint32_t idx0 = (uint32_t)(s0 + yc0 * Wi + xc) * 32u;
    uint32_t idx1 = (uint32_t)(s0 + yc1 * Wi + xc) * 32u;

    sm[gl][ln] = make_uint4(idx0, idx1, wp0, wp1);
    // intra-wave LDS write->read: compiler-inserted lgkmcnt orders it

    const uint32_t* plane =
        val_pair + (size_t)(n * HEADS + h) * PLANE + 2 * ln;
    float a0 = 0.f, a1 = 0.f;
#pragma unroll
    for (int p = 0; p < 16; ++p) {
        uint4 ent = sm[gl][p];
        uint2 r0 = *(const uint2*)(plane + ent.x);
        uint2 r1 = *(const uint2*)(plane + ent.y);
        a0 = dot2bf(r0.x, ent.z, a0);
        a1 = dot2bf(r0.y, ent.z, a1);
        a0 = dot2bf(r1.x, ent.w, a0);
        a1 = dot2bf(r1.y, ent.w, a1);
    }
    uint32_t r = ((uint32_t)f2bf(a1) << 16) | (uint32_t)f2bf(a0);
    sampled[(size_t)qg * 128 + h * 16 + ln] = r;
}

// ---------------------------------------------------------------------------
// K3: fused out-proj + residual + LayerNorm (unchanged from R5).
// ---------------------------------------------------------------------------
__global__ __launch_bounds__(256) void out_ln_gemm(
    const ushort* __restrict__ sampled, const ushort* __restrict__ w_out_t,
    const float* __restrict__ b_out,    const float* __restrict__ src,
    const float* __restrict__ gamma,    const float* __restrict__ beta,
    float* __restrict__ out)
{
    const int tid = threadIdx.x;
    const int m0  = blockIdx.x * 64;
    const int wv = tid >> 6, lane = tid & 63;
    const int quad = lane >> 4, ln = lane & 15;

    const int row_a = m0 + wv * 16 + ln;
    const bool va = row_a < NQ;
    const ushort* ap = sampled + (size_t)row_a * 256 + quad * 8;
    bf16x8 af[8];
#pragma unroll
    for (int s = 0; s < 8; ++s) {
        bf16x8 v = {0, 0, 0, 0, 0, 0, 0, 0};
        if (va) v = *(const bf16x8*)(ap + s * 32);
        af[s] = v;
    }

    f32x4 acc[4][4];
#pragma unroll
    for (int by = 0; by < 4; ++by)
#pragma unroll
        for (int t = 0; t < 4; ++t) acc[by][t] = (f32x4){0, 0, 0, 0};

    const ushort* bp = w_out_t + (size_t)ln * 256 + quad * 8;
#pragma unroll
    for (int by = 0; by < 4; ++by) {
        bf16x8 bfr[4][8];
#pragma unroll
        for (int t = 0; t < 4; ++t)
#pragma unroll
            for (int s = 0; s < 8; ++s)
                bfr[t][s] = *(const bf16x8*)(bp + (size_t)(by * 64 + t * 16) * 256 + s * 32);
#pragma unroll
        for (int s = 0; s < 8; ++s)
#pragma unroll
            for (int t = 0; t < 4; ++t)
                acc[by][t] = __builtin_amdgcn_mfma_f32_16x16x32_bf16(af[s], bfr[t][s], acc[by][t], 0, 0, 0);
    }

    // epilogue: residual + bias, LN stats per row (16 cols/thread, x16 lanes)
#pragma unroll
    for (int reg = 0; reg < 4; ++reg) {
        const int row = m0 + wv * 16 + quad * 4 + reg;
        const bool vr = row < NQ;
        float xv[16];
        float s = 0.f, s2 = 0.f;
#pragma unroll
        for (int bt = 0; bt < 16; ++bt) {
            int col = bt * 16 + ln;
            float v = acc[bt >> 2][bt & 3][reg] + b_out[col];
            if (vr) v += src[(size_t)row * 256 + col];
            xv[bt] = v;
            s += v; s2 += v * v;
        }
#pragma unroll
        for (int o = 8; o; o >>= 1) {
            s  += __shfl_xor(s, o, 16);
            s2 += __shfl_xor(s2, o, 16);
        }
        float mu  = s * (1.f / 256.f);
        float var = s2 * (1.f / 256.f) - mu * mu;
        float rs  = rsqrtf(var + 1e-5f);
        if (vr) {
#pragma unroll
            for (int bt = 0; bt < 16; ++bt) {
                int col = bt * 16 + ln;
                out[(size_t)row * 256 + col] = (xv[bt] - mu) * rs * gamma[col] + beta[col];
            }
        }
    }
}

// ---------------------------------------------------------------------------
extern "C" void kernel_launch(void* const* d_in, const int* in_sizes, int n_in,
                              void* d_out, int out_size, void* d_ws, size_t ws_size,
                              hipStream_t stream)
{
    const float* src     = (const float*)d_in[0];
    const float* refp    = (const float*)d_in[1];
    const float* w_value = (const float*)d_in[4];
    const float* b_value = (const float*)d_in[5];
    const float* w_off   = (const float*)d_in[6];
    const float* b_off   = (const float*)d_in[7];
    const float* w_attn  = (const float*)d_in[8];
    const float* b_attn  = (const float*)d_in[9];
    const float* w_out   = (const float*)d_in[10];
    const float* b_out   = (const float*)d_in[11];
    const float* gamma   = (const float*)d_in[12];
    const float* beta    = (const float*)d_in[13];

    char* ws = (char*)d_ws;
    ushort*   val_t    = (ushort*)  (ws);                   // 12,533,760 B
    uint32_t* val_pair = (uint32_t*)(ws + 12533760);        // 25,067,520 B
    ushort*   src_bf   = (ushort*)  (ws + 12533760);        // alias of val_pair
                                                            // (src_bf dead before
                                                            //  pair_kernel writes)
    float*    off_raw  = (float*)   (ws + 37601280);        // 25,067,520 B
    float*    attn_raw = (float*)   (ws + 62668800);        // 12,533,760 B
    uint32_t* sampled  = (uint32_t*)(ws + 62668800);        // alias of attn_raw (safe: K2)
    ushort*   B_pack   = (ushort*)  (ws + 75202560);        //    327,680 B
    ushort*   w_out_t  = (ushort*)  (ws + 75530240);        //    131,072 B
    float*    b_pack   = (float*)   (ws + 75661312);        //      2,560 B
    float*    out      = (float*)d_out;

    conv_kernel<<<899, 256, 0, stream>>>(w_value, w_off, w_attn, b_value, b_off,
                                         b_attn, w_out, B_pack, w_out_t, b_pack);
    src2bf_kernel<<<6120, 256, 0, stream>>>(src, src_bf);
    proj_gemm<<<dim3(64, 10), 256, 0, stream>>>(src_bf, B_pack, b_pack, val_t,
                                                off_raw, attn_raw);
    pair_kernel<<<24480, 256, 0, stream>>>(val_t, val_pair);
    sample_kernel<<<12240, 256, 0, stream>>>(refp, val_pair, off_raw, attn_raw,
                                             sampled);
    out_ln_gemm<<<383, 256, 0, stream>>>((const ushort*)sampled, w_out_t, b_out,
                                         src, gamma, beta, out);
}

// Round 8
// 235.592 us; speedup vs baseline: 1.2111x; 1.0857x over previous
//
#include <hip/hip_runtime.h>
#include <cstdint>
#include <cstddef>

#define D 256
#define HEADS 8
#define HD 32
#define NB 2
#define LQ 12240
#define NQ (NB * LQ)        // 24480
#define PLANE (LQ * HD)     // 391680 elements per (n,h) plane

typedef __attribute__((ext_vector_type(8))) short bf16x8;
typedef __attribute__((ext_vector_type(4))) float f32x4;
typedef __bf16 bf16x2 __attribute__((ext_vector_type(2)));

__device__ __forceinline__ ushort f2bf(float f) {
    union { float f; uint32_t u; } c; c.f = f;
    uint32_t u = c.u;
    uint32_t r = (u + 0x7fffu + ((u >> 16) & 1u)) >> 16;   // RNE, finite inputs
    return (ushort)r;
}

// c += a_pair . b_pair  (bf16 pairs packed in u32, f32 accumulate)
__device__ __forceinline__ float dot2bf(uint32_t a, uint32_t b, float c) {
#if __has_builtin(__builtin_amdgcn_fdot2_f32_bf16)
    return __builtin_amdgcn_fdot2_f32_bf16(__builtin_bit_cast(bf16x2, a),
                                           __builtin_bit_cast(bf16x2, b), c, false);
#else
    float alo = __uint_as_float(a << 16), ahi = __uint_as_float(a & 0xffff0000u);
    float blo = __uint_as_float(b << 16), bhi = __uint_as_float(b & 0xffff0000u);
    return c + alo * blo + ahi * bhi;
#endif
}

// ---------------------------------------------------------------------------
// K0: weight/bias conversion (unchanged).
// ---------------------------------------------------------------------------
__global__ __launch_bounds__(256) void conv_kernel(
    const float* __restrict__ w_value, const float* __restrict__ w_off,
    const float* __restrict__ w_attn,  const float* __restrict__ b_value,
    const float* __restrict__ b_off,   const float* __restrict__ b_attn,
    const float* __restrict__ w_out,
    ushort* __restrict__ B_pack, ushort* __restrict__ w_out_t,
    float* __restrict__ b_pack)
{
    const int b = blockIdx.x, k = threadIdx.x;
    if (b < 640) {
        float v;
        if (b < 256)      v = w_value[(size_t)k * 256 + b];
        else if (b < 512) v = w_off[(size_t)k * 256 + (b - 256)];
        else              v = w_attn[(size_t)k * 128 + (b - 512)];
        B_pack[(size_t)b * 256 + k] = f2bf(v);
    } else if (b < 896) {
        int n = b - 640;
        w_out_t[(size_t)n * 256 + k] = f2bf(w_out[(size_t)k * 256 + n]);
    } else if (b == 896) {
        b_pack[k] = b_value[k];
    } else if (b == 897) {
        b_pack[256 + k] = b_off[k];
    } else {
        if (k < 128) b_pack[512 + k] = b_attn[k];
    }
}

// ---------------------------------------------------------------------------
// K0b: src fp32 -> bf16 (row-major, 4 elems/thread).
// ---------------------------------------------------------------------------
__global__ __launch_bounds__(256) void src2bf_kernel(
    const float* __restrict__ src, ushort* __restrict__ src_bf)
{
    const size_t i = ((size_t)blockIdx.x * 256 + threadIdx.x) * 4;
    float4 v = *(const float4*)(src + i);
    ushort4 o;
    o.x = f2bf(v.x); o.y = f2bf(v.y); o.z = f2bf(v.z); o.w = f2bf(v.w);
    *(ushort4*)(src_bf + i) = o;
}

// ---------------------------------------------------------------------------
// K1: fused projections via MFMA -- B-stationary in registers (unchanged,
// known good).
// ---------------------------------------------------------------------------
__global__ __launch_bounds__(256, 2) void proj_gemm(
    const ushort* __restrict__ src_bf, const ushort* __restrict__ B_pack,
    const float* __restrict__ b_pack,
    ushort* __restrict__ val_t, float* __restrict__ off_raw,
    float* __restrict__ attn_raw)
{
    const int tid = threadIdx.x;
    const int wv = tid >> 6, lane = tid & 63;
    const int quad = lane >> 4, ln = lane & 15;
    const int mc = blockIdx.x;          // 0..63
    const int by = blockIdx.y;          // 0..9

    const ushort* bp = B_pack + (size_t)(by * 64 + ln) * 256 + quad * 8;
    bf16x8 bfr[4][8];
#pragma unroll
    for (int t = 0; t < 4; ++t)
#pragma unroll
        for (int s = 0; s < 8; ++s)
            bfr[t][s] = *(const bf16x8*)(bp + (size_t)t * (16 * 256) + s * 32);

    float bias[4];
#pragma unroll
    for (int t = 0; t < 4; ++t) bias[t] = b_pack[by * 64 + t * 16 + ln];

    for (int i = 0; i < 6; ++i) {
        const int base = (mc * 6 + i) * 64;
        if (base >= NQ) break;
        const int row_a = base + wv * 16 + ln;
        const bool va = row_a < NQ;
        const ushort* ap = src_bf + (size_t)row_a * 256 + quad * 8;

        bf16x8 af[8];
#pragma unroll
        for (int s = 0; s < 8; ++s) {
            bf16x8 v = {0, 0, 0, 0, 0, 0, 0, 0};
            if (va) v = *(const bf16x8*)(ap + s * 32);
            af[s] = v;
        }

        f32x4 acc[4] = {{0,0,0,0},{0,0,0,0},{0,0,0,0},{0,0,0,0}};
#pragma unroll
        for (int s = 0; s < 8; ++s)
#pragma unroll
            for (int t = 0; t < 4; ++t)
                acc[t] = __builtin_amdgcn_mfma_f32_16x16x32_bf16(af[s], bfr[t][s], acc[t], 0, 0, 0);

        if (by < 4) {
#pragma unroll
            for (int t = 0; t < 4; ++t) {
                const int n_g = by * 64 + t * 16 + ln;
                const int h = n_g >> 5, hd = n_g & 31;
#pragma unroll
                for (int reg = 0; reg < 4; ++reg) {
                    int row = base + wv * 16 + quad * 4 + reg;
                    if (row < NQ) {
                        int nb = row >= LQ; int ql = row - nb * LQ;
                        val_t[(((size_t)(nb * 8 + h)) * LQ + ql) * 32 + hd] =
                            f2bf(acc[t][reg] + bias[t]);
                    }
                }
            }
        } else if (by < 8) {
#pragma unroll
            for (int t = 0; t < 4; ++t) {
                const int col = (by - 4) * 64 + t * 16 + ln;
#pragma unroll
                for (int reg = 0; reg < 4; ++reg) {
                    int row = base + wv * 16 + quad * 4 + reg;
                    if (row < NQ)
                        off_raw[(size_t)row * 256 + col] = acc[t][reg] + bias[t];
                }
            }
        } else {
#pragma unroll
            for (int t = 0; t < 4; ++t) {
                const int col = (by - 8) * 64 + t * 16 + ln;
#pragma unroll
                for (int reg = 0; reg < 4; ++reg) {
                    int row = base + wv * 16 + quad * 4 + reg;
                    if (row < NQ)
                        attn_raw[(size_t)row * 128 + col] = acc[t][reg] + bias[t];
                }
            }
        }
    }
}

// ---------------------------------------------------------------------------
// K1b: build x-pair table (unchanged).
// ---------------------------------------------------------------------------
__global__ __launch_bounds__(256) void pair_kernel(
    const ushort* __restrict__ val_t, uint32_t* __restrict__ val_pair)
{
    const uint32_t i = blockIdx.x * 256 + threadIdx.x;   // < 6,266,880
    const uint32_t c = i & 31;
    const uint32_t rest = i >> 5;                        // plane*12240 + pos
    const uint32_t plane = rest / LQ;
    const uint32_t pos = rest - plane * LQ;
    int l = (pos >= 9216) + (pos >= 11520) + (pos >= 12096);
    uint32_t s0 = (l > 0 ? 9216u : 0u) + (l > 1 ? 2304u : 0u) + (l > 2 ? 576u : 0u);
    uint32_t Wi = 96u >> l;
    uint32_t p = pos - s0;
    uint32_t q = (p / 3u) >> (5 - l);          // p / Wi  (Wi = 3<<(5-l))
    uint32_t xr = p - q * Wi;                  // p % Wi
    uint32_t nxt = (xr == Wi - 1u) ? pos : pos + 1u;
    uint32_t lo = val_t[(size_t)plane * PLANE + pos * 32 + c];
    uint32_t hi = val_t[(size_t)plane * PLANE + nxt * 32 + c];
    val_pair[i] = lo | (hi << 16);
}

// ---------------------------------------------------------------------------
// K2: softmax + sampling + bilinear gather via x-pair table + dot2
// (unchanged).
// ---------------------------------------------------------------------------
__global__ __launch_bounds__(256) void sample_kernel(
    const float* __restrict__ ref_pts,
    const uint32_t* __restrict__ val_pair,
    const float* __restrict__ off_raw,
    const float* attn_raw,
    uint32_t* sampled)
{
    __shared__ uint4 sm[16][16];
    const int gl = threadIdx.x >> 4;
    const int ln = threadIdx.x & 15;
    const int g  = blockIdx.x * 16 + gl;
    const int qg = g >> 3, h = g & 7;
    const int n  = (qg >= LQ) ? 1 : 0;
    const int l  = ln >> 2;

    float a = attn_raw[(size_t)qg * 128 + h * 16 + ln];
    float m = a;
#pragma unroll
    for (int s = 8; s; s >>= 1) m = fmaxf(m, __shfl_xor(m, s, 16));
    float e = __expf(a - m);
    float ssum = e;
#pragma unroll
    for (int s = 8; s; s >>= 1) ssum += __shfl_xor(ssum, s, 16);
    float aw = e / ssum;

    float ox = off_raw[(size_t)qg * 256 + h * 32 + ln * 2 + 0];
    float oy = off_raw[(size_t)qg * 256 + h * 32 + ln * 2 + 1];
    float rx = ref_pts[(qg * 4 + l) * 2 + 0];
    float ry = ref_pts[(qg * 4 + l) * 2 + 1];

    const int Wi = 96 >> l;
    const int Hi = Wi;
    const int s0 = (l > 0 ? 9216 : 0) + (l > 1 ? 2304 : 0) + (l > 2 ? 576 : 0);
    const float Wf = (float)Wi, Hf = (float)Hi;

    float x = (rx + ox / Wf) * Wf - 0.5f;
    float y = (ry + oy / Hf) * Hf - 0.5f;
    float x0f = floorf(x), y0f = floorf(y);
    float lx = x - x0f, ly = y - y0f;
    int x0 = (int)x0f, y0 = (int)y0f;

    float wy0 = (y0 >= 0 && y0 < Hi) ? (1.f - ly) : 0.f;
    float wy1 = (y0 + 1 >= 0 && y0 + 1 < Hi) ? ly : 0.f;
    int yc0 = min(max(y0, 0), Hi - 1);
    int yc1 = min(max(y0 + 1, 0), Hi - 1);
    float wl = (x0 >= 0 && x0 < Wi) ? (1.f - lx) : 0.f;
    float wh = (x0 + 1 >= 0 && x0 + 1 < Wi) ? lx : 0.f;
    float pl, ph;
    int xe;
    if (x0 < 0) { pl = wh; ph = 0.f; xe = x0 + 1; }
    else        { pl = wl; ph = wh;  xe = x0; }
    int xc = min(max(xe, 0), Wi - 1);
    pl *= aw; ph *= aw;

    uint32_t wp0 = ((uint32_t)f2bf(ph * wy0) << 16) | (uint32_t)f2bf(pl * wy0);
    uint32_t wp1 = ((uint32_t)f2bf(ph * wy1) << 16) | (uint32_t)f2bf(pl * wy1);
    uint32_t idx0 = (uint32_t)(s0 + yc0 * Wi + xc) * 32u;
    uint32_t idx1 = (uint32_t)(s0 + yc1 * Wi + xc) * 32u;

    sm[gl][ln] = make_uint4(idx0, idx1, wp0, wp1);
    // intra-wave LDS write->read: same-wave DS ops execute in order

    const uint32_t* plane =
        val_pair + (size_t)(n * HEADS + h) * PLANE + 2 * ln;
    float a0 = 0.f, a1 = 0.f;
#pragma unroll
    for (int p = 0; p < 16; ++p) {
        uint4 ent = sm[gl][p];
        uint2 r0 = *(const uint2*)(plane + ent.x);
        uint2 r1 = *(const uint2*)(plane + ent.y);
        a0 = dot2bf(r0.x, ent.z, a0);
        a1 = dot2bf(r0.y, ent.z, a1);
        a0 = dot2bf(r1.x, ent.w, a0);
        a1 = dot2bf(r1.y, ent.w, a1);
    }
    uint32_t r = ((uint32_t)f2bf(a1) << 16) | (uint32_t)f2bf(a0);
    sampled[(size_t)qg * 128 + h * 16 + ln] = r;
}

// ---------------------------------------------------------------------------
// K3a: out-projection, proj_gemm pattern (B-stationary, (256,2), known-good
// register shape: af 32 + bfr 128 + acc 16 = 176 VGPRs).
// Grid (128 M-chunks x 4 N-tiles) = 512 blocks (2/CU even); 3 M-tiles of 64
// rows per block.  x = acc + b_out + src (fp32).
// ---------------------------------------------------------------------------
__global__ __launch_bounds__(256, 2) void out_gemm(
    const ushort* __restrict__ sampled, const ushort* __restrict__ w_out_t,
    const float* __restrict__ b_out,    const float* __restrict__ src,
    float* __restrict__ x)
{
    const int tid = threadIdx.x;
    const int wv = tid >> 6, lane = tid & 63;
    const int quad = lane >> 4, ln = lane & 15;
    const int mc = blockIdx.x;          // 0..127
    const int by = blockIdx.y;          // 0..3

    const ushort* bp = w_out_t + (size_t)(by * 64 + ln) * 256 + quad * 8;
    bf16x8 bfr[4][8];
#pragma unroll
    for (int t = 0; t < 4; ++t)
#pragma unroll
        for (int s = 0; s < 8; ++s)
            bfr[t][s] = *(const bf16x8*)(bp + (size_t)t * (16 * 256) + s * 32);

    float bias[4];
#pragma unroll
    for (int t = 0; t < 4; ++t) bias[t] = b_out[by * 64 + t * 16 + ln];

    for (int i = 0; i < 3; ++i) {
        const int base = (mc * 3 + i) * 64;
        if (base >= NQ) break;
        const int row_a = base + wv * 16 + ln;
        const bool va = row_a < NQ;
        const ushort* ap = sampled + (size_t)row_a * 256 + quad * 8;

        bf16x8 af[8];
#pragma unroll
        for (int s = 0; s < 8; ++s) {
            bf16x8 v = {0, 0, 0, 0, 0, 0, 0, 0};
            if (va) v = *(const bf16x8*)(ap + s * 32);
            af[s] = v;
        }

        f32x4 acc[4] = {{0,0,0,0},{0,0,0,0},{0,0,0,0},{0,0,0,0}};
#pragma unroll
        for (int s = 0; s < 8; ++s)
#pragma unroll
            for (int t = 0; t < 4; ++t)
                acc[t] = __builtin_amdgcn_mfma_f32_16x16x32_bf16(af[s], bfr[t][s], acc[t], 0, 0, 0);

#pragma unroll
        for (int t = 0; t < 4; ++t) {
            const int col = by * 64 + t * 16 + ln;
#pragma unroll
            for (int reg = 0; reg < 4; ++reg) {
                int row = base + wv * 16 + quad * 4 + reg;
                if (row < NQ)
                    x[(size_t)row * 256 + col] =
                        acc[t][reg] + bias[t] + src[(size_t)row * 256 + col];
            }
        }
    }
}

// ---------------------------------------------------------------------------
// K3b: LayerNorm.  One wave per row, float4 per lane (known good from R2-R5).
// ---------------------------------------------------------------------------
__global__ __launch_bounds__(256) void ln_kernel(
    const float* __restrict__ x, const float* __restrict__ gamma,
    const float* __restrict__ beta, float* __restrict__ out)
{
    const int row  = blockIdx.x * 4 + (threadIdx.x >> 6);
    const int lane = threadIdx.x & 63;
    float4 v = *(const float4*)(x + (size_t)row * 256 + lane * 4);
    float s  = v.x + v.y + v.z + v.w;
    float s2 = v.x * v.x + v.y * v.y + v.z * v.z + v.w * v.w;
#pragma unroll
    for (int o = 32; o; o >>= 1) {
        s  += __shfl_xor(s, o);
        s2 += __shfl_xor(s2, o);
    }
    float mu  = s * (1.f / 256.f);
    float var = s2 * (1.f / 256.f) - mu * mu;
    float rs  = rsqrtf(var + 1e-5f);
    float4 g = *(const float4*)(gamma + lane * 4);
    float4 b = *(const float4*)(beta + lane * 4);
    float4 o4;
    o4.x = (v.x - mu) * rs * g.x + b.x;
    o4.y = (v.y - mu) * rs * g.y + b.y;
    o4.z = (v.z - mu) * rs * g.z + b.z;
    o4.w = (v.w - mu) * rs * g.w + b.w;
    *(float4*)(out + (size_t)row * 256 + lane * 4) = o4;
}

// ---------------------------------------------------------------------------
extern "C" void kernel_launch(void* const* d_in, const int* in_sizes, int n_in,
                              void* d_out, int out_size, void* d_ws, size_t ws_size,
                              hipStream_t stream)
{
    const float* src     = (const float*)d_in[0];
    const float* refp    = (const float*)d_in[1];
    const float* w_value = (const float*)d_in[4];
    const float* b_value = (const float*)d_in[5];
    const float* w_off   = (const float*)d_in[6];
    const float* b_off   = (const float*)d_in[7];
    const float* w_attn  = (const float*)d_in[8];
    const float* b_attn  = (const float*)d_in[9];
    const float* w_out   = (const float*)d_in[10];
    const float* b_out   = (const float*)d_in[11];
    const float* gamma   = (const float*)d_in[12];
    const float* beta    = (const float*)d_in[13];

    char* ws = (char*)d_ws;
    ushort*   val_t    = (ushort*)  (ws);                   // 12,533,760 B
    uint32_t* val_pair = (uint32_t*)(ws + 12533760);        // 25,067,520 B
    ushort*   src_bf   = (ushort*)  (ws + 12533760);        // alias of val_pair
                                                            // (src_bf dead before
                                                            //  pair_kernel writes)
    float*    off_raw  = (float*)   (ws + 37601280);        // 25,067,520 B
    float*    attn_raw = (float*)   (ws + 62668800);        // 12,533,760 B
    uint32_t* sampled  = (uint32_t*)(ws + 62668800);        // alias of attn_raw (safe: K2)
    ushort*   B_pack   = (ushort*)  (ws + 75202560);        //    327,680 B
    ushort*   w_out_t  = (ushort*)  (ws + 75530240);        //    131,072 B
    float*    b_pack   = (float*)   (ws + 75661312);        //      2,560 B
    float*    x        = off_raw;                           // alias (off_raw dead after K2)
    float*    out      = (float*)d_out;

    conv_kernel<<<899, 256, 0, stream>>>(w_value, w_off, w_attn, b_value, b_off,
                                         b_attn, w_out, B_pack, w_out_t, b_pack);
    src2bf_kernel<<<6120, 256, 0, stream>>>(src, src_bf);
    proj_gemm<<<dim3(64, 10), 256, 0, stream>>>(src_bf, B_pack, b_pack, val_t,
                                                off_raw, attn_raw);
    pair_kernel<<<24480, 256, 0, stream>>>(val_t, val_pair);
    sample_kernel<<<12240, 256, 0, stream>>>(refp, val_pair, off_raw, attn_raw,
                                             sampled);
    out_gemm<<<dim3(128, 4), 256, 0, stream>>>((const ushort*)sampled, w_out_t,
                                               b_out, src, x);
    ln_kernel<<<6120, 256, 0, stream>>>(x, gamma, beta, out);
}

// Round 9
// 231.351 us; speedup vs baseline: 1.2333x; 1.0183x over previous
//
#include <hip/hip_runtime.h>
#include <cstdint>
#include <cstddef>

#define D 256
#define HEADS 8
#define HD 32
#define NB 2
#define LQ 12240
#define NQ (NB * LQ)        // 24480
#define PLANE (LQ * HD)     // 391680 elements per (n,h) plane

typedef __attribute__((ext_vector_type(8))) short bf16x8;
typedef __attribute__((ext_vector_type(4))) float f32x4;
typedef __bf16 bf16x2 __attribute__((ext_vector_type(2)));

__device__ __forceinline__ ushort f2bf(float f) {
    union { float f; uint32_t u; } c; c.f = f;
    uint32_t u = c.u;
    uint32_t r = (u + 0x7fffu + ((u >> 16) & 1u)) >> 16;   // RNE, finite inputs
    return (ushort)r;
}

// c += a_pair . b_pair  (bf16 pairs packed in u32, f32 accumulate)
__device__ __forceinline__ float dot2bf(uint32_t a, uint32_t b, float c) {
#if __has_builtin(__builtin_amdgcn_fdot2_f32_bf16)
    return __builtin_amdgcn_fdot2_f32_bf16(__builtin_bit_cast(bf16x2, a),
                                           __builtin_bit_cast(bf16x2, b), c, false);
#else
    float alo = __uint_as_float(a << 16), ahi = __uint_as_float(a & 0xffff0000u);
    float blo = __uint_as_float(b << 16), bhi = __uint_as_float(b & 0xffff0000u);
    return c + alo * blo + ahi * bhi;
#endif
}

// ---------------------------------------------------------------------------
// K0: weight/bias conversion + src fp32->bf16 (merged; branches block-uniform).
// blocks 0..898: weights/biases as before.  blocks 899..7018: src2bf.
// ---------------------------------------------------------------------------
__global__ __launch_bounds__(256) void conv_kernel(
    const float* __restrict__ w_value, const float* __restrict__ w_off,
    const float* __restrict__ w_attn,  const float* __restrict__ b_value,
    const float* __restrict__ b_off,   const float* __restrict__ b_attn,
    const float* __restrict__ w_out,   const float* __restrict__ src,
    ushort* __restrict__ B_pack, ushort* __restrict__ w_out_t,
    float* __restrict__ b_pack, ushort* __restrict__ src_bf)
{
    const int b = blockIdx.x, k = threadIdx.x;
    if (b >= 899) {
        const size_t i = ((size_t)(b - 899) * 256 + k) * 4;
        float4 v = *(const float4*)(src + i);
        ushort4 o;
        o.x = f2bf(v.x); o.y = f2bf(v.y); o.z = f2bf(v.z); o.w = f2bf(v.w);
        *(ushort4*)(src_bf + i) = o;
        return;
    }
    if (b < 640) {
        float v;
        if (b < 256)      v = w_value[(size_t)k * 256 + b];
        else if (b < 512) v = w_off[(size_t)k * 256 + (b - 256)];
        else              v = w_attn[(size_t)k * 128 + (b - 512)];
        B_pack[(size_t)b * 256 + k] = f2bf(v);
    } else if (b < 896) {
        int n = b - 640;
        w_out_t[(size_t)n * 256 + k] = f2bf(w_out[(size_t)k * 256 + n]);
    } else if (b == 896) {
        b_pack[k] = b_value[k];
    } else if (b == 897) {
        b_pack[256 + k] = b_off[k];
    } else {
        if (k < 128) b_pack[512 + k] = b_attn[k];
    }
}

// ---------------------------------------------------------------------------
// K1: fused projections via MFMA -- B-stationary in registers (unchanged,
// known good).
// ---------------------------------------------------------------------------
__global__ __launch_bounds__(256, 2) void proj_gemm(
    const ushort* __restrict__ src_bf, const ushort* __restrict__ B_pack,
    const float* __restrict__ b_pack,
    ushort* __restrict__ val_t, float* __restrict__ off_raw,
    float* __restrict__ attn_raw)
{
    const int tid = threadIdx.x;
    const int wv = tid >> 6, lane = tid & 63;
    const int quad = lane >> 4, ln = lane & 15;
    const int mc = blockIdx.x;          // 0..63
    const int by = blockIdx.y;          // 0..9

    const ushort* bp = B_pack + (size_t)(by * 64 + ln) * 256 + quad * 8;
    bf16x8 bfr[4][8];
#pragma unroll
    for (int t = 0; t < 4; ++t)
#pragma unroll
        for (int s = 0; s < 8; ++s)
            bfr[t][s] = *(const bf16x8*)(bp + (size_t)t * (16 * 256) + s * 32);

    float bias[4];
#pragma unroll
    for (int t = 0; t < 4; ++t) bias[t] = b_pack[by * 64 + t * 16 + ln];

    for (int i = 0; i < 6; ++i) {
        const int base = (mc * 6 + i) * 64;
        if (base >= NQ) break;
        const int row_a = base + wv * 16 + ln;
        const bool va = row_a < NQ;
        const ushort* ap = src_bf + (size_t)row_a * 256 + quad * 8;

        bf16x8 af[8];
#pragma unroll
        for (int s = 0; s < 8; ++s) {
            bf16x8 v = {0, 0, 0, 0, 0, 0, 0, 0};
            if (va) v = *(const bf16x8*)(ap + s * 32);
            af[s] = v;
        }

        f32x4 acc[4] = {{0,0,0,0},{0,0,0,0},{0,0,0,0},{0,0,0,0}};
#pragma unroll
        for (int s = 0; s < 8; ++s)
#pragma unroll
            for (int t = 0; t < 4; ++t)
                acc[t] = __builtin_amdgcn_mfma_f32_16x16x32_bf16(af[s], bfr[t][s], acc[t], 0, 0, 0);

        if (by < 4) {
#pragma unroll
            for (int t = 0; t < 4; ++t) {
                const int n_g = by * 64 + t * 16 + ln;
                const int h = n_g >> 5, hd = n_g & 31;
#pragma unroll
                for (int reg = 0; reg < 4; ++reg) {
                    int row = base + wv * 16 + quad * 4 + reg;
                    if (row < NQ) {
                        int nb = row >= LQ; int ql = row - nb * LQ;
                        val_t[(((size_t)(nb * 8 + h)) * LQ + ql) * 32 + hd] =
                            f2bf(acc[t][reg] + bias[t]);
                    }
                }
            }
        } else if (by < 8) {
#pragma unroll
            for (int t = 0; t < 4; ++t) {
                const int col = (by - 4) * 64 + t * 16 + ln;
#pragma unroll
                for (int reg = 0; reg < 4; ++reg) {
                    int row = base + wv * 16 + quad * 4 + reg;
                    if (row < NQ)
                        off_raw[(size_t)row * 256 + col] = acc[t][reg] + bias[t];
                }
            }
        } else {
#pragma unroll
            for (int t = 0; t < 4; ++t) {
                const int col = (by - 8) * 64 + t * 16 + ln;
#pragma unroll
                for (int reg = 0; reg < 4; ++reg) {
                    int row = base + wv * 16 + quad * 4 + reg;
                    if (row < NQ)
                        attn_raw[(size_t)row * 128 + col] = acc[t][reg] + bias[t];
                }
            }
        }
    }
}

// ---------------------------------------------------------------------------
// K1b: build x-pair table (unchanged).
// ---------------------------------------------------------------------------
__global__ __launch_bounds__(256) void pair_kernel(
    const ushort* __restrict__ val_t, uint32_t* __restrict__ val_pair)
{
    const uint32_t i = blockIdx.x * 256 + threadIdx.x;   // < 6,266,880
    const uint32_t c = i & 31;
    const uint32_t rest = i >> 5;                        // plane*12240 + pos
    const uint32_t plane = rest / LQ;
    const uint32_t pos = rest - plane * LQ;
    int l = (pos >= 9216) + (pos >= 11520) + (pos >= 12096);
    uint32_t s0 = (l > 0 ? 9216u : 0u) + (l > 1 ? 2304u : 0u) + (l > 2 ? 576u : 0u);
    uint32_t Wi = 96u >> l;
    uint32_t p = pos - s0;
    uint32_t q = (p / 3u) >> (5 - l);          // p / Wi  (Wi = 3<<(5-l))
    uint32_t xr = p - q * Wi;                  // p % Wi
    uint32_t nxt = (xr == Wi - 1u) ? pos : pos + 1u;
    uint32_t lo = val_t[(size_t)plane * PLANE + pos * 32 + c];
    uint32_t hi = val_t[(size_t)plane * PLANE + nxt * 32 + c];
    val_pair[i] = lo | (hi << 16);
}

// ---------------------------------------------------------------------------
// K2: softmax + sampling + bilinear gather via x-pair table + dot2.
// XCD-partitioned: h = blockIdx%8 (round-robin XCD heuristic) -> each XCD
// touches only its head's 2 planes (3.1 MB < 4 MB L2).  Block = 16 queries
// of ONE head.  Gather loads preloaded in chunks of 8 points into register
// arrays (16 outstanding dwordx2/wave) to hide L2 latency.
// `sampled` aliases `attn_raw` word-exactly per lane -> safe.
// ---------------------------------------------------------------------------
__global__ __launch_bounds__(256) void sample_kernel(
    const float* __restrict__ ref_pts,
    const uint32_t* __restrict__ val_pair,
    const float* __restrict__ off_raw,
    const float* attn_raw,
    uint32_t* sampled)
{
    __shared__ uint4 sm[16][16];
    const int gl = threadIdx.x >> 4;
    const int ln = threadIdx.x & 15;
    const int h     = blockIdx.x & 7;        // -> XCD id (heuristic)
    const int chunk = blockIdx.x >> 3;       // 0..1529
    const int qg = chunk * 16 + gl;
    const int n  = (qg >= LQ) ? 1 : 0;
    const int l  = ln >> 2;

    // softmax over 16 (level,point) logits of this head
    float a = attn_raw[(size_t)qg * 128 + h * 16 + ln];
    float m = a;
#pragma unroll
    for (int s = 8; s; s >>= 1) m = fmaxf(m, __shfl_xor(m, s, 16));
    float e = __expf(a - m);
    float ssum = e;
#pragma unroll
    for (int s = 8; s; s >>= 1) ssum += __shfl_xor(ssum, s, 16);
    float aw = e / ssum;

    float ox = off_raw[(size_t)qg * 256 + h * 32 + ln * 2 + 0];
    float oy = off_raw[(size_t)qg * 256 + h * 32 + ln * 2 + 1];
    float rx = ref_pts[(qg * 4 + l) * 2 + 0];
    float ry = ref_pts[(qg * 4 + l) * 2 + 1];

    const int Wi = 96 >> l;
    const int Hi = Wi;
    const int s0 = (l > 0 ? 9216 : 0) + (l > 1 ? 2304 : 0) + (l > 2 ? 576 : 0);
    const float Wf = (float)Wi, Hf = (float)Hi;

    float x = (rx + ox / Wf) * Wf - 0.5f;
    float y = (ry + oy / Hf) * Hf - 0.5f;
    float x0f = floorf(x), y0f = floorf(y);
    float lx = x - x0f, ly = y - y0f;
    int x0 = (int)x0f, y0 = (int)y0f;

    float wy0 = (y0 >= 0 && y0 < Hi) ? (1.f - ly) : 0.f;
    float wy1 = (y0 + 1 >= 0 && y0 + 1 < Hi) ? ly : 0.f;
    int yc0 = min(max(y0, 0), Hi - 1);
    int yc1 = min(max(y0 + 1, 0), Hi - 1);
    float wl = (x0 >= 0 && x0 < Wi) ? (1.f - lx) : 0.f;
    float wh = (x0 + 1 >= 0 && x0 + 1 < Wi) ? lx : 0.f;
    float pl, ph;
    int xe;
    if (x0 < 0) { pl = wh; ph = 0.f; xe = x0 + 1; }
    else        { pl = wl; ph = wh;  xe = x0; }
    int xc = min(max(xe, 0), Wi - 1);
    pl *= aw; ph *= aw;

    uint32_t wp0 = ((uint32_t)f2bf(ph * wy0) << 16) | (uint32_t)f2bf(pl * wy0);
    uint32_t wp1 = ((uint32_t)f2bf(ph * wy1) << 16) | (uint32_t)f2bf(pl * wy1);
    uint32_t idx0 = (uint32_t)(s0 + yc0 * Wi + xc) * 32u;
    uint32_t idx1 = (uint32_t)(s0 + yc1 * Wi + xc) * 32u;

    sm[gl][ln] = make_uint4(idx0, idx1, wp0, wp1);
    // intra-wave LDS write->read: same-wave DS ops execute in order

    const uint32_t* plane =
        val_pair + (size_t)(n * HEADS + h) * PLANE + 2 * ln;
    float a0 = 0.f, a1 = 0.f;
#pragma unroll
    for (int c = 0; c < 2; ++c) {
        uint2 r0v[8], r1v[8];
        uint32_t wz[8], ww[8];
#pragma unroll
        for (int p = 0; p < 8; ++p) {
            uint4 ent = sm[gl][c * 8 + p];
            r0v[p] = *(const uint2*)(plane + ent.x);
            r1v[p] = *(const uint2*)(plane + ent.y);
            wz[p] = ent.z; ww[p] = ent.w;
        }
#pragma unroll
        for (int p = 0; p < 8; ++p) {
            a0 = dot2bf(r0v[p].x, wz[p], a0);
            a1 = dot2bf(r0v[p].y, wz[p], a1);
            a0 = dot2bf(r1v[p].x, ww[p], a0);
            a1 = dot2bf(r1v[p].y, ww[p], a1);
        }
    }
    uint32_t r = ((uint32_t)f2bf(a1) << 16) | (uint32_t)f2bf(a0);
    sampled[(size_t)qg * 128 + h * 16 + ln] = r;
}

// ---------------------------------------------------------------------------
// K3a: out-projection, proj_gemm pattern (unchanged, known good).
// ---------------------------------------------------------------------------
__global__ __launch_bounds__(256, 2) void out_gemm(
    const ushort* __restrict__ sampled, const ushort* __restrict__ w_out_t,
    const float* __restrict__ b_out,    const float* __restrict__ src,
    float* __restrict__ x)
{
    const int tid = threadIdx.x;
    const int wv = tid >> 6, lane = tid & 63;
    const int quad = lane >> 4, ln = lane & 15;
    const int mc = blockIdx.x;          // 0..127
    const int by = blockIdx.y;          // 0..3

    const ushort* bp = w_out_t + (size_t)(by * 64 + ln) * 256 + quad * 8;
    bf16x8 bfr[4][8];
#pragma unroll
    for (int t = 0; t < 4; ++t)
#pragma unroll
        for (int s = 0; s < 8; ++s)
            bfr[t][s] = *(const bf16x8*)(bp + (size_t)t * (16 * 256) + s * 32);

    float bias[4];
#pragma unroll
    for (int t = 0; t < 4; ++t) bias[t] = b_out[by * 64 + t * 16 + ln];

    for (int i = 0; i < 3; ++i) {
        const int base = (mc * 3 + i) * 64;
        if (base >= NQ) break;
        const int row_a = base + wv * 16 + ln;
        const bool va = row_a < NQ;
        const ushort* ap = sampled + (size_t)row_a * 256 + quad * 8;

        bf16x8 af[8];
#pragma unroll
        for (int s = 0; s < 8; ++s) {
            bf16x8 v = {0, 0, 0, 0, 0, 0, 0, 0};
            if (va) v = *(const bf16x8*)(ap + s * 32);
            af[s] = v;
        }

        f32x4 acc[4] = {{0,0,0,0},{0,0,0,0},{0,0,0,0},{0,0,0,0}};
#pragma unroll
        for (int s = 0; s < 8; ++s)
#pragma unroll
            for (int t = 0; t < 4; ++t)
                acc[t] = __builtin_amdgcn_mfma_f32_16x16x32_bf16(af[s], bfr[t][s], acc[t], 0, 0, 0);

#pragma unroll
        for (int t = 0; t < 4; ++t) {
            const int col = by * 64 + t * 16 + ln;
#pragma unroll
            for (int reg = 0; reg < 4; ++reg) {
                int row = base + wv * 16 + quad * 4 + reg;
                if (row < NQ)
                    x[(size_t)row * 256 + col] =
                        acc[t][reg] + bias[t] + src[(size_t)row * 256 + col];
            }
        }
    }
}

// ---------------------------------------------------------------------------
// K3b: LayerNorm.  One wave per row, float4 per lane (unchanged, known good).
// ---------------------------------------------------------------------------
__global__ __launch_bounds__(256) void ln_kernel(
    const float* __restrict__ x, const float* __restrict__ gamma,
    const float* __restrict__ beta, float* __restrict__ out)
{
    const int row  = blockIdx.x * 4 + (threadIdx.x >> 6);
    const int lane = threadIdx.x & 63;
    float4 v = *(const float4*)(x + (size_t)row * 256 + lane * 4);
    float s  = v.x + v.y + v.z + v.w;
    float s2 = v.x * v.x + v.y * v.y + v.z * v.z + v.w * v.w;
#pragma unroll
    for (int o = 32; o; o >>= 1) {
        s  += __shfl_xor(s, o);
        s2 += __shfl_xor(s2, o);
    }
    float mu  = s * (1.f / 256.f);
    float var = s2 * (1.f / 256.f) - mu * mu;
    float rs  = rsqrtf(var + 1e-5f);
    float4 g = *(const float4*)(gamma + lane * 4);
    float4 b = *(const float4*)(beta + lane * 4);
    float4 o4;
    o4.x = (v.x - mu) * rs * g.x + b.x;
    o4.y = (v.y - mu) * rs * g.y + b.y;
    o4.z = (v.z - mu) * rs * g.z + b.z;
    o4.w = (v.w - mu) * rs * g.w + b.w;
    *(float4*)(out + (size_t)row * 256 + lane * 4) = o4;
}

// ---------------------------------------------------------------------------
extern "C" void kernel_launch(void* const* d_in, const int* in_sizes, int n_in,
                              void* d_out, int out_size, void* d_ws, size_t ws_size,
                              hipStream_t stream)
{
    const float* src     = (const float*)d_in[0];
    const float* refp    = (const float*)d_in[1];
    const float* w_value = (const float*)d_in[4];
    const float* b_value = (const float*)d_in[5];
    const float* w_off   = (const float*)d_in[6];
    const float* b_off   = (const float*)d_in[7];
    const float* w_attn  = (const float*)d_in[8];
    const float* b_attn  = (const float*)d_in[9];
    const float* w_out   = (const float*)d_in[10];
    const float* b_out   = (const float*)d_in[11];
    const float* gamma   = (const float*)d_in[12];
    const float* beta    = (const float*)d_in[13];

    char* ws = (char*)d_ws;
    ushort*   val_t    = (ushort*)  (ws);                   // 12,533,760 B
    uint32_t* val_pair = (uint32_t*)(ws + 12533760);        // 25,067,520 B
    ushort*   src_bf   = (ushort*)  (ws + 12533760);        // alias of val_pair
                                                            // (src_bf dead before
                                                            //  pair_kernel writes)
    float*    off_raw  = (float*)   (ws + 37601280);        // 25,067,520 B
    float*    attn_raw = (float*)   (ws + 62668800);        // 12,533,760 B
    uint32_t* sampled  = (uint32_t*)(ws + 62668800);        // alias of attn_raw (safe: K2)
    ushort*   B_pack   = (ushort*)  (ws + 75202560);        //    327,680 B
    ushort*   w_out_t  = (ushort*)  (ws + 75530240);        //    131,072 B
    float*    b_pack   = (float*)   (ws + 75661312);        //      2,560 B
    float*    x        = off_raw;                           // alias (off_raw dead after K2)
    float*    out      = (float*)d_out;

    conv_kernel<<<7019, 256, 0, stream>>>(w_value, w_off, w_attn, b_value, b_off,
                                          b_attn, w_out, src, B_pack, w_out_t,
                                          b_pack, src_bf);
    proj_gemm<<<dim3(64, 10), 256, 0, stream>>>(src_bf, B_pack, b_pack, val_t,
                                                off_raw, attn_raw);
    pair_kernel<<<24480, 256, 0, stream>>>(val_t, val_pair);
    sample_kernel<<<12240, 256, 0, stream>>>(refp, val_pair, off_raw, attn_raw,
                                             sampled);
    out_gemm<<<dim3(128, 4), 256, 0, stream>>>((const ushort*)sampled, w_out_t,
                                               b_out, src, x);
    ln_kernel<<<6120, 256, 0, stream>>>(x, gamma, beta, out);
}